// Round 4
// baseline (49835.141 us; speedup 1.0000x reference)
//
#include <hip/hip_runtime.h>

#define NN   4096
#define OBSN 2048
#define S1   2047
#define S2   2047
#define HID  128
#define INDIM 100

typedef float v2f __attribute__((ext_vector_type(2)));
typedef float v4f __attribute__((ext_vector_type(4)));

// Barrier WITHOUT vmcnt(0) drain: all cross-thread per-step dataflow is LDS,
// so lgkmcnt(0) suffices; global prefetches stay in flight across steps.
__device__ __forceinline__ void bar() {
    asm volatile("s_waitcnt lgkmcnt(0)\n\ts_barrier" ::: "memory");
}

// DPP cross-lane move (VALU-speed, no LDS): returns x from lane per CTRL.
// CTRL: quad_perm[1,0,3,2]=0xB1 (xor1), [2,3,0,1]=0x4E (xor2),
//       row_shr:4=0x114, row_shr:8=0x118. bound_ctrl=1 -> OOB lanes give 0.
template <int CTRL>
__device__ __forceinline__ float dpp_mov(float x) {
    return __builtin_bit_cast(float, __builtin_amdgcn_update_dpp(
        0, __builtin_bit_cast(int, x), CTRL, 0xF, 0xF, true));
}

__device__ __forceinline__ float sigm(float x) {
    return 1.0f / (1.0f + __expf(-x));
}
__device__ __forceinline__ float tanh_(float x) {
    float e = __expf(2.0f * x);
    return 1.0f - 2.0f / (e + 1.0f);
}

// Exact reference-semantics cell classification (strict < both sides,
// boundary-equality excluded via a+b==7). bx[j] = CST[j]+cx EXACTLY as ref.
__device__ __forceinline__ unsigned long long classify(float x, float y,
                                                       const float* bx, const float* by) {
    int a = 0, b = 0, c = 0, d = 0;
#pragma unroll
    for (int j = 0; j < 7; j++) {
        a += bx[j] < x;
        b += x < bx[j];
        c += by[j] < y;
        d += y < by[j];
    }
    if (a >= 1 && a <= 6 && (a + b) == 7 && c >= 1 && c <= 6 && (c + d) == 7)
        return 1ull << ((a - 1) * 6 + (c - 1));
    return 0ull;
}

__device__ __forceinline__ float hsum32(const float* p) {
    const v4f* q = (const v4f*)p;
    const v4f s0 = q[0] + q[1], s1 = q[2] + q[3];
    const v4f s2 = q[4] + q[5], s3 = q[6] + q[7];
    const v4f s = (s0 + s1) + (s2 + s3);
    return (s.x + s.y) + (s.z + s.w);
}

// ---------- kernel 1: phase-1 occupancy masks (parallel over t) ----------
__global__ __launch_bounds__(256) void k_occ1(const float* __restrict__ obs,
                                              const float* __restrict__ oth,
                                              unsigned long long* __restrict__ occm) {
    const int t = blockIdx.x;
    const int slice = t + 1;
    const float cx = obs[slice * 2 + 0];
    const float cy = obs[slice * 2 + 1];
    const float CST[7] = {-1.5f, -1.0f, -0.5f, 0.0f, 0.5f, 1.0f, 1.5f};
    float bx[7], by[7];
#pragma unroll
    for (int j = 0; j < 7; j++) { bx[j] = CST[j] + cx; by[j] = CST[j] + cy; }

    const float2* p = (const float2*)(oth + (size_t)slice * NN * 2);
    unsigned long long m = 0ull;
#pragma unroll 4
    for (int i = 0; i < 16; i++) {
        float2 q = p[i * 256 + threadIdx.x];
        if (q.x > bx[0] && q.x < bx[6] && q.y > by[0] && q.y < by[6])
            m |= classify(q.x, q.y, bx, by);
    }
#pragma unroll
    for (int off = 32; off > 0; off >>= 1) m |= __shfl_down(m, off);
    __shared__ unsigned long long sm[4];
    if ((threadIdx.x & 63) == 0) sm[threadIdx.x >> 6] = m;
    __syncthreads();
    if (threadIdx.x == 0) occm[t] = sm[0] | sm[1] | sm[2] | sm[3];
}

// ---------- kernel 2: transpose occ columns of W_ih into [36][512] ----------
__global__ void k_tr(const float* __restrict__ W_ih, float* __restrict__ WT) {
    WT[blockIdx.x * 512 + threadIdx.x] = W_ih[threadIdx.x * INDIM + 64 + blockIdx.x];
}

// ---------- kernel 3: phase-1 gate preactivation G1[t][512] ----------
__global__ __launch_bounds__(256) void k_g1(const float* __restrict__ obs,
                                            const float* __restrict__ W_emb,
                                            const float* __restrict__ b_emb,
                                            const float* __restrict__ W_ih,
                                            const float* __restrict__ b_ih,
                                            const float* __restrict__ b_hh,
                                            const unsigned long long* __restrict__ occm,
                                            float* __restrict__ G1) {
    const int t = blockIdx.x;
    const int tid = threadIdx.x;
    __shared__ __align__(16) float e[64];
    const float d0 = obs[(t + 1) * 2 + 0] - obs[t * 2 + 0];
    const float d1 = obs[(t + 1) * 2 + 1] - obs[t * 2 + 1];
    if (tid < 64) {
        float v = W_emb[tid * 2 + 0] * d0 + W_emb[tid * 2 + 1] * d1 + b_emb[tid];
        e[tid] = v > 0.0f ? v : 0.0f;
    }
    __syncthreads();
    const unsigned long long m = occm[t];
#pragma unroll
    for (int rr = 0; rr < 2; rr++) {
        const int r = tid + rr * 256;
        const float* wr = W_ih + r * INDIM;
        float s = b_ih[r] + b_hh[r];
        float4 acc = {0.f, 0.f, 0.f, 0.f};
        const float4* w4 = (const float4*)wr;
        const float4* e4 = (const float4*)e;
#pragma unroll
        for (int q = 0; q < 16; q++) {
            float4 w = w4[q], ev = e4[q];
            acc.x += w.x * ev.x; acc.y += w.y * ev.y;
            acc.z += w.z * ev.z; acc.w += w.w * ev.w;
        }
        s += (acc.x + acc.y) + (acc.z + acc.w);
        unsigned long long mm = m;
        while (mm) {
            int j = __ffsll((long long)mm) - 1;
            mm &= mm - 1;
            s += wr[64 + j];
        }
        G1[t * 512 + r] = s;
    }
}

// ---------- kernel 4: sequential LSTM ----------
// 512 threads = 8 waves = 2/SIMD. Thread = (unit u = wv*16 + (lane>>2),
// col-quarter k = lane&3). All cross-lane traffic is DPP (quad_perm for the
// gate butterfly, row_shr for the W_out partials) or rare LDS atomics --
// no ds_bpermute chains on the critical path.
__global__ __launch_bounds__(512, 2)
__attribute__((amdgpu_waves_per_eu(2, 2)))
void k_seq(const float* __restrict__ obs,
           const float* __restrict__ oth,
           const float* __restrict__ W_emb,
           const float* __restrict__ b_emb,
           const float* __restrict__ W_ih,
           const float* __restrict__ b_ih,
           const float* __restrict__ W_hh,
           const float* __restrict__ b_hh,
           const float* __restrict__ W_out,
           const float* __restrict__ b_out,
           const float* __restrict__ G1,
           const float* __restrict__ WT,
           float* __restrict__ out) {
    const int tid  = threadIdx.x;
    const int wv   = tid >> 6;
    const int lane = tid & 63;
    const int u    = wv * 16 + (lane >> 2);
    const int k    = lane & 3;

    // --- persistent W_hh fragment: rows u+128g, cols [32k, 32k+32) ---
    v2f whh[4][16];
#pragma unroll
    for (int g = 0; g < 4; g++) {
        const v2f* src = (const v2f*)(W_hh + (u + 128 * g) * HID + 32 * k);
#pragma unroll
        for (int j = 0; j < 16; j++) whh[g][j] = src[j];
    }
    float biasg[4];
#pragma unroll
    for (int g = 0; g < 4; g++) biasg[g] = b_ih[u + 128 * g] + b_hh[u + 128 * g];

    const float woA = W_out[k * HID + u];          // this thread's out-dim = k
    const float woB = W_out[4 * HID + u];          // dim 4, on k==0 lanes
    const float bo0 = b_out[0], bo1 = b_out[1];
    const float boT = (tid < 5) ? b_out[tid] : 0.0f;
    float we0 = 0.f, we1 = 0.f, be = 0.f;
    if (tid < 64) { we0 = W_emb[tid * 2]; we1 = W_emb[tid * 2 + 1]; be = b_emb[tid]; }
    const float obsA0 = obs[(S1 - 1) * 2], obsA1 = obs[(S1 - 1) * 2 + 1];
    const float obsB0 = obs[S1 * 2],       obsB1 = obs[S1 * 2 + 1];

    __shared__ __align__(16) float hbuf[2][HID];
    __shared__ __align__(16) float e_lds[64];
    __shared__ __align__(16) float red1[2][5][32];
    __shared__ __align__(16) float red2[5][32];
    __shared__ unsigned int smlo[2], smhi[2];

    if (tid < HID) hbuf[0][tid] = 0.0f;
    float c = 0.0f;
    float p1x = 0.f, p1y = 0.f, p2x = 0.f, p2y = 0.f;
    int p = 0;
    __syncthreads();

    // G1 prefetch for t=0
    v4f g1v;
    {
        const float* gp = G1 + u;
        g1v.x = gp[0]; g1v.y = gp[128]; g1v.z = gp[256]; g1v.w = gp[384];
    }

    // writer predicate for the W_out partials: last quad of each 16-row
    const bool wrRed = (lane & 12) == 12;
    const int  slot  = wv * 4 + (lane >> 4);

    // =============== phase 1: 1 barrier/step ===============
    for (int t = 0; t < S1; ++t) {
        const v4f cur = g1v;
        const int tn = (t + 1 < S1) ? t + 1 : t;
        {
            const float* gp = G1 + tn * 512 + u;
            g1v.x = gp[0]; g1v.y = gp[128]; g1v.z = gp[256]; g1v.w = gp[384];
        }

        v2f a0 = {0.f, 0.f}, a1 = {0.f, 0.f}, a2 = {0.f, 0.f}, a3 = {0.f, 0.f};
        const v4f* h4 = ((const v4f*)hbuf[p]) + k * 8;
#pragma unroll
        for (int qq = 0; qq < 8; qq++) {
            const int q = (qq + 2 * k) & 7;      // bank-conflict-free rotation
            const v4f hv = h4[q];
            const v2f hl = hv.xy, hh2 = hv.zw;
            a0 = whh[0][2*q] * hl + a0;  a0 = whh[0][2*q+1] * hh2 + a0;
            a1 = whh[1][2*q] * hl + a1;  a1 = whh[1][2*q+1] * hh2 + a1;
            a2 = whh[2][2*q] * hl + a2;  a2 = whh[2][2*q+1] * hh2 + a2;
            a3 = whh[3][2*q] * hl + a3;  a3 = whh[3][2*q+1] * hh2 + a3;
        }
        float pg0 = (a0.x + a0.y) + ((k == 0) ? cur.x : 0.0f);
        float pg1 = (a1.x + a1.y) + ((k == 0) ? cur.y : 0.0f);
        float pg2 = (a2.x + a2.y) + ((k == 0) ? cur.z : 0.0f);
        float pg3 = (a3.x + a3.y) + ((k == 0) ? cur.w : 0.0f);
        // quad butterfly via DPP (xor1, xor2) -- all 4 lanes get full sums
        pg0 += dpp_mov<0xB1>(pg0); pg0 += dpp_mov<0x4E>(pg0);
        pg1 += dpp_mov<0xB1>(pg1); pg1 += dpp_mov<0x4E>(pg1);
        pg2 += dpp_mov<0xB1>(pg2); pg2 += dpp_mov<0x4E>(pg2);
        pg3 += dpp_mov<0xB1>(pg3); pg3 += dpp_mov<0x4E>(pg3);

        const float gi = sigm(pg0), gf = sigm(pg1);
        const float gG = tanh_(pg2), go = sigm(pg3);
        c = gf * c + gi * gG;
        const float h = go * tanh_(c);
        if (k == 0) hbuf[p ^ 1][u] = h;

        float pd = woA * h;
        float pe = (k == 0) ? woB * h : 0.0f;
        pd += dpp_mov<0x114>(pd); pd += dpp_mov<0x118>(pd);   // row_shr 4,8
        pe += dpp_mov<0x114>(pe); pe += dpp_mov<0x118>(pe);
        if (wrRed) {
            red1[p][k][slot] = pd;
            if (k == 0) red1[p][4][slot] = pe;
        }
        bar();
        if (tid < 5) out[t * 5 + tid] = hsum32(red1[p][tid]) + boT;
        if (t >= S1 - 2) {   // uniform branch: handoff positions to all threads
            const float n0 = hsum32(red1[p][0]) + bo0;
            const float n1 = hsum32(red1[p][1]) + bo1;
            if (t == S1 - 2) { p1x = obsA0 + n0; p1y = obsA1 + n1; }
            else             { p2x = obsB0 + n0; p2y = obsB1 + n1; }
        }
        p ^= 1;
    }

    // --- phase-2-only weights ---
    v2f wie[4][8];
#pragma unroll
    for (int g = 0; g < 4; g++) {
        const v2f* src = (const v2f*)(W_ih + (u + 128 * g) * INDIM + 16 * k);
#pragma unroll
        for (int j = 0; j < 8; j++) wie[g][j] = src[j];
    }

    float pcx = p2x, pcy = p2y;
    float dx = p2x - p1x, dy = p2y - p1y;

    v4f nb[4];
    {
        const v4f* s0 = (const v4f*)(oth + (size_t)OBSN * NN * 2);
#pragma unroll
        for (int i = 0; i < 4; i++) nb[i] = s0[i * 512 + tid];
    }
    if (tid < 64) {   // e for s=0
        float v = we0 * dx + we1 * dy + be;
        e_lds[tid] = v > 0.0f ? v : 0.0f;
    }
    if (tid == 0) { smlo[0] = 0; smlo[1] = 0; smhi[0] = 0; smhi[1] = 0; }
    const float CST[7] = {-1.5f, -1.0f, -0.5f, 0.0f, 0.5f, 1.0f, 1.5f};
    bar();   // init visible before first-step atomics

    // =============== phase 2: 2 barriers/step ===============
    for (int s = 0; s < S2; ++s) {
        float bx[7], by[7];
#pragma unroll
        for (int j = 0; j < 7; j++) { bx[j] = CST[j] + pcx; by[j] = CST[j] + pcy; }

        unsigned long long m = 0ull;
#pragma unroll
        for (int i = 0; i < 4; i++) {
            const v4f q = nb[i];
            if (q.x > bx[0] && q.x < bx[6] && q.y > by[0] && q.y < by[6])
                m |= classify(q.x, q.y, bx, by);
            if (q.z > bx[0] && q.z < bx[6] && q.w > by[0] && q.w < by[6])
                m |= classify(q.z, q.w, bx, by);
        }
        {   // next-slice prefetch; lgkm-only barriers never drain it
            const int sn = (s + 1 < S2) ? s + 1 : s;
            const v4f* pf = (const v4f*)(oth + (size_t)(OBSN + sn) * NN * 2);
#pragma unroll
            for (int i = 0; i < 4; i++) nb[i] = pf[i * 512 + tid];
        }
        // rare LDS atomics replace the 12-bpermute 64-bit OR reduction
        {
            const unsigned int lo = (unsigned int)m;
            const unsigned int hi = (unsigned int)(m >> 32);
            if (lo) atomicOr(&smlo[s & 1], lo);
            if (hi) atomicOr(&smhi[s & 1], hi);
        }
        bar();   // B1: mask + e_lds ready

        const unsigned long long mm =
            (unsigned long long)smlo[s & 1] | ((unsigned long long)smhi[s & 1] << 32);
        float og0 = (k == 0) ? biasg[0] : 0.0f;
        float og1 = (k == 0) ? biasg[1] : 0.0f;
        float og2 = (k == 0) ? biasg[2] : 0.0f;
        float og3 = (k == 0) ? biasg[3] : 0.0f;
        {
            unsigned long long mm2 = mm;
            int idx = 0;
            while (mm2) {
                const int j = __ffsll((long long)mm2) - 1;
                mm2 &= mm2 - 1;
                if ((idx & 3) == k) {
                    const float* wc = WT + j * 512 + u;
                    og0 += wc[0];
                    og1 += wc[128];
                    og2 += wc[256];
                    og3 += wc[384];
                }
                idx++;
            }
        }

        v2f a0 = {0.f, 0.f}, a1 = {0.f, 0.f}, a2 = {0.f, 0.f}, a3 = {0.f, 0.f};
        {
            const v4f* e4 = ((const v4f*)e_lds) + k * 4;
#pragma unroll
            for (int qq = 0; qq < 4; qq++) {
                const int q = (qq + k) & 3;       // rotation
                const v4f ev = e4[q];
                const v2f el = ev.xy, eh = ev.zw;
                a0 = wie[0][2*q] * el + a0;  a0 = wie[0][2*q+1] * eh + a0;
                a1 = wie[1][2*q] * el + a1;  a1 = wie[1][2*q+1] * eh + a1;
                a2 = wie[2][2*q] * el + a2;  a2 = wie[2][2*q+1] * eh + a2;
                a3 = wie[3][2*q] * el + a3;  a3 = wie[3][2*q+1] * eh + a3;
            }
            const v4f* h4 = ((const v4f*)hbuf[p]) + k * 8;
#pragma unroll
            for (int qq = 0; qq < 8; qq++) {
                const int q = (qq + 2 * k) & 7;   // rotation
                const v4f hv = h4[q];
                const v2f hl = hv.xy, hh2 = hv.zw;
                a0 = whh[0][2*q] * hl + a0;  a0 = whh[0][2*q+1] * hh2 + a0;
                a1 = whh[1][2*q] * hl + a1;  a1 = whh[1][2*q+1] * hh2 + a1;
                a2 = whh[2][2*q] * hl + a2;  a2 = whh[2][2*q+1] * hh2 + a2;
                a3 = whh[3][2*q] * hl + a3;  a3 = whh[3][2*q+1] * hh2 + a3;
            }
        }
        float pg0 = og0 + (a0.x + a0.y);
        float pg1 = og1 + (a1.x + a1.y);
        float pg2 = og2 + (a2.x + a2.y);
        float pg3 = og3 + (a3.x + a3.y);
        pg0 += dpp_mov<0xB1>(pg0); pg0 += dpp_mov<0x4E>(pg0);
        pg1 += dpp_mov<0xB1>(pg1); pg1 += dpp_mov<0x4E>(pg1);
        pg2 += dpp_mov<0xB1>(pg2); pg2 += dpp_mov<0x4E>(pg2);
        pg3 += dpp_mov<0xB1>(pg3); pg3 += dpp_mov<0x4E>(pg3);

        const float gi = sigm(pg0), gf = sigm(pg1);
        const float gG = tanh_(pg2), go = sigm(pg3);
        c = gf * c + gi * gG;
        const float h = go * tanh_(c);
        if (k == 0) hbuf[p ^ 1][u] = h;

        float pd = woA * h;
        float pe = (k == 0) ? woB * h : 0.0f;
        pd += dpp_mov<0x114>(pd); pd += dpp_mov<0x118>(pd);
        pe += dpp_mov<0x114>(pe); pe += dpp_mov<0x118>(pe);
        if (wrRed) {
            red2[k][slot] = pd;
            if (k == 0) red2[4][slot] = pe;
        }
        bar();   // B2: h + red ready

        const float n0 = hsum32(red2[0]) + bo0;
        const float n1 = hsum32(red2[1]) + bo1;
        if (tid < 5) out[(S1 + s) * 5 + tid] = hsum32(red2[tid]) + boT;
        if (tid == 0) { smlo[s & 1] = 0; smhi[s & 1] = 0; }   // re-arm for s+2
        dx = n0; dy = n1;
        pcx += n0; pcy += n1;
        if (tid < 64) {   // e for s+1; ordered vs step-s readers by B2
            float v = we0 * dx + we1 * dy + be;
            e_lds[tid] = v > 0.0f ? v : 0.0f;
        }
        p ^= 1;
    }
}

// ---------- launcher ----------
extern "C" void kernel_launch(void* const* d_in, const int* in_sizes, int n_in,
                              void* d_out, int out_size, void* d_ws, size_t ws_size,
                              hipStream_t stream) {
    const float* obs   = (const float*)d_in[0];
    const float* oth   = (const float*)d_in[1];
    const float* W_emb = (const float*)d_in[2];
    const float* b_emb = (const float*)d_in[3];
    const float* W_ih  = (const float*)d_in[4];
    const float* b_ih  = (const float*)d_in[5];
    const float* W_hh  = (const float*)d_in[6];
    const float* b_hh  = (const float*)d_in[7];
    const float* W_out = (const float*)d_in[8];
    const float* b_out = (const float*)d_in[9];
    float* out = (float*)d_out;

    unsigned long long* occm = (unsigned long long*)d_ws;
    float* G1 = (float*)((char*)d_ws + 16384);
    float* WT = (float*)((char*)d_ws + 16384 + (size_t)S1 * 512 * 4);

    k_occ1<<<S1, 256, 0, stream>>>(obs, oth, occm);
    k_tr<<<36, 512, 0, stream>>>(W_ih, WT);
    k_g1<<<S1, 256, 0, stream>>>(obs, W_emb, b_emb, W_ih, b_ih, b_hh, occm, G1);
    k_seq<<<1, 512, 0, stream>>>(obs, oth, W_emb, b_emb, W_ih, b_ih, W_hh, b_hh,
                                 W_out, b_out, G1, WT, out);
}

// Round 5
// 49703.583 us; speedup vs baseline: 1.0026x; 1.0026x over previous
//
#include <hip/hip_runtime.h>

#define NN   4096
#define OBSN 2048
#define S1   2047
#define S2   2047
#define HID  128
#define INDIM 100

typedef float v2f __attribute__((ext_vector_type(2)));
typedef float v4f __attribute__((ext_vector_type(4)));

// Barrier WITHOUT vmcnt(0) drain: all cross-thread per-step dataflow is LDS,
// so lgkmcnt(0) suffices; global prefetches stay in flight across steps.
__device__ __forceinline__ void bar() {
    asm volatile("s_waitcnt lgkmcnt(0)\n\ts_barrier" ::: "memory");
}

// DPP cross-lane move: quad_perm[1,0,3,2]=0xB1 (xor1), [2,3,0,1]=0x4E (xor2),
// row_shr:4=0x114, row_shr:8=0x118. bound_ctrl=1 -> OOB lanes contribute 0.
template <int CTRL>
__device__ __forceinline__ float dpp_mov(float x) {
    return __builtin_bit_cast(float, __builtin_amdgcn_update_dpp(
        0, __builtin_bit_cast(int, x), CTRL, 0xF, 0xF, true));
}

__device__ __forceinline__ float sigm(float x) {
    return 1.0f / (1.0f + __expf(-x));
}
__device__ __forceinline__ float tanh_(float x) {
    float e = __expf(2.0f * x);
    return 1.0f - 2.0f / (e + 1.0f);
}

// Exact reference-semantics cell classification (strict < both sides,
// boundary-equality excluded via a+b==7). bx[j] = CST[j]+cx EXACTLY as ref.
__device__ __forceinline__ unsigned long long classify(float x, float y,
                                                       const float* bx, const float* by) {
    int a = 0, b = 0, c = 0, d = 0;
#pragma unroll
    for (int j = 0; j < 7; j++) {
        a += bx[j] < x;
        b += x < bx[j];
        c += by[j] < y;
        d += y < by[j];
    }
    if (a >= 1 && a <= 6 && (a + b) == 7 && c >= 1 && c <= 6 && (c + d) == 7)
        return 1ull << ((a - 1) * 6 + (c - 1));
    return 0ull;
}

__device__ __forceinline__ float hsum32(const float* p) {
    const v4f* q = (const v4f*)p;
    const v4f s0 = q[0] + q[1], s1 = q[2] + q[3];
    const v4f s2 = q[4] + q[5], s3 = q[6] + q[7];
    const v4f s = (s0 + s1) + (s2 + s3);
    return (s.x + s.y) + (s.z + s.w);
}

// ---------- kernel 1: phase-1 occupancy masks (parallel over t) ----------
__global__ __launch_bounds__(256) void k_occ1(const float* __restrict__ obs,
                                              const float* __restrict__ oth,
                                              unsigned long long* __restrict__ occm) {
    const int t = blockIdx.x;
    const int slice = t + 1;
    const float cx = obs[slice * 2 + 0];
    const float cy = obs[slice * 2 + 1];
    const float CST[7] = {-1.5f, -1.0f, -0.5f, 0.0f, 0.5f, 1.0f, 1.5f};
    float bx[7], by[7];
#pragma unroll
    for (int j = 0; j < 7; j++) { bx[j] = CST[j] + cx; by[j] = CST[j] + cy; }

    const float2* p = (const float2*)(oth + (size_t)slice * NN * 2);
    unsigned long long m = 0ull;
#pragma unroll 4
    for (int i = 0; i < 16; i++) {
        float2 q = p[i * 256 + threadIdx.x];
        if (q.x > bx[0] && q.x < bx[6] && q.y > by[0] && q.y < by[6])
            m |= classify(q.x, q.y, bx, by);
    }
#pragma unroll
    for (int off = 32; off > 0; off >>= 1) m |= __shfl_down(m, off);
    __shared__ unsigned long long sm[4];
    if ((threadIdx.x & 63) == 0) sm[threadIdx.x >> 6] = m;
    __syncthreads();
    if (threadIdx.x == 0) occm[t] = sm[0] | sm[1] | sm[2] | sm[3];
}

// ---------- kernel 2: transpose occ columns of W_ih into [36][512] ----------
__global__ void k_tr(const float* __restrict__ W_ih, float* __restrict__ WT) {
    WT[blockIdx.x * 512 + threadIdx.x] = W_ih[threadIdx.x * INDIM + 64 + blockIdx.x];
}

// ---------- kernel 3: phase-1 gate preactivation G1[t][512] ----------
__global__ __launch_bounds__(256) void k_g1(const float* __restrict__ obs,
                                            const float* __restrict__ W_emb,
                                            const float* __restrict__ b_emb,
                                            const float* __restrict__ W_ih,
                                            const float* __restrict__ b_ih,
                                            const float* __restrict__ b_hh,
                                            const unsigned long long* __restrict__ occm,
                                            float* __restrict__ G1) {
    const int t = blockIdx.x;
    const int tid = threadIdx.x;
    __shared__ __align__(16) float e[64];
    const float d0 = obs[(t + 1) * 2 + 0] - obs[t * 2 + 0];
    const float d1 = obs[(t + 1) * 2 + 1] - obs[t * 2 + 1];
    if (tid < 64) {
        float v = W_emb[tid * 2 + 0] * d0 + W_emb[tid * 2 + 1] * d1 + b_emb[tid];
        e[tid] = v > 0.0f ? v : 0.0f;
    }
    __syncthreads();
    const unsigned long long m = occm[t];
#pragma unroll
    for (int rr = 0; rr < 2; rr++) {
        const int r = tid + rr * 256;
        const float* wr = W_ih + r * INDIM;
        float s = b_ih[r] + b_hh[r];
        float4 acc = {0.f, 0.f, 0.f, 0.f};
        const float4* w4 = (const float4*)wr;
        const float4* e4 = (const float4*)e;
#pragma unroll
        for (int q = 0; q < 16; q++) {
            float4 w = w4[q], ev = e4[q];
            acc.x += w.x * ev.x; acc.y += w.y * ev.y;
            acc.z += w.z * ev.z; acc.w += w.w * ev.w;
        }
        s += (acc.x + acc.y) + (acc.z + acc.w);
        unsigned long long mm = m;
        while (mm) {
            int j = __ffsll((long long)mm) - 1;
            mm &= mm - 1;
            s += wr[64 + j];
        }
        G1[t * 512 + r] = s;
    }
}

// ---------- kernel 4a: phase-1 sequential LSTM ----------
// 512 threads = 8 waves = 2/SIMD (R3-proven config: launch_bounds(512,2),
// VGPR=128 + AGPR-parked weights, NO waves_per_eu -> no scratch spills).
// Thread = (unit u = wv*16 + (lane>>2), col-quarter k = lane&3).
// Cross-lane: DPP quad butterfly for gates, DPP row_shr for W_out partials.
__global__ __launch_bounds__(512, 2)
void k_seq1(const float* __restrict__ obs,
            const float* __restrict__ W_hh,
            const float* __restrict__ W_out,
            const float* __restrict__ b_out,
            const float* __restrict__ G1,
            float* __restrict__ out,
            float* __restrict__ st) {
    const int tid  = threadIdx.x;
    const int wv   = tid >> 6;
    const int lane = tid & 63;
    const int u    = wv * 16 + (lane >> 2);
    const int k    = lane & 3;

    v2f whh[4][16];
#pragma unroll
    for (int g = 0; g < 4; g++) {
        const v2f* src = (const v2f*)(W_hh + (u + 128 * g) * HID + 32 * k);
#pragma unroll
        for (int j = 0; j < 16; j++) whh[g][j] = src[j];
    }
    const float woA = W_out[k * HID + u];
    const float woB = W_out[4 * HID + u];
    const float bo0 = b_out[0], bo1 = b_out[1];
    const float boT = (tid < 5) ? b_out[tid] : 0.0f;
    const float obsA0 = obs[(S1 - 1) * 2], obsA1 = obs[(S1 - 1) * 2 + 1];
    const float obsB0 = obs[S1 * 2],       obsB1 = obs[S1 * 2 + 1];

    __shared__ __align__(16) float hbuf[2][HID];
    __shared__ __align__(16) float red1[2][5][32];

    if (tid < HID) hbuf[0][tid] = 0.0f;
    float c = 0.0f, h_last = 0.0f;
    float p1x = 0.f, p1y = 0.f, p2x = 0.f, p2y = 0.f;
    int p = 0;
    __syncthreads();

    v4f g1v;
    {
        const float* gp = G1 + u;
        g1v.x = gp[0]; g1v.y = gp[128]; g1v.z = gp[256]; g1v.w = gp[384];
    }
    const bool wrRed = (lane & 12) == 12;
    const int  slot  = wv * 4 + (lane >> 4);

    for (int t = 0; t < S1; ++t) {
        const v4f cur = g1v;
        const int tn = (t + 1 < S1) ? t + 1 : t;
        {
            const float* gp = G1 + tn * 512 + u;
            g1v.x = gp[0]; g1v.y = gp[128]; g1v.z = gp[256]; g1v.w = gp[384];
        }

        v2f a0 = {0.f, 0.f}, a1 = {0.f, 0.f}, a2 = {0.f, 0.f}, a3 = {0.f, 0.f};
        const v4f* h4 = ((const v4f*)hbuf[p]) + k * 8;
#pragma unroll
        for (int qq = 0; qq < 8; qq++) {
            const int q = (qq + 2 * k) & 7;      // bank-conflict-free rotation
            const v4f hv = h4[q];
            const v2f hl = hv.xy, hh2 = hv.zw;
            a0 = whh[0][2*q] * hl + a0;  a0 = whh[0][2*q+1] * hh2 + a0;
            a1 = whh[1][2*q] * hl + a1;  a1 = whh[1][2*q+1] * hh2 + a1;
            a2 = whh[2][2*q] * hl + a2;  a2 = whh[2][2*q+1] * hh2 + a2;
            a3 = whh[3][2*q] * hl + a3;  a3 = whh[3][2*q+1] * hh2 + a3;
        }
        float pg0 = (a0.x + a0.y) + ((k == 0) ? cur.x : 0.0f);
        float pg1 = (a1.x + a1.y) + ((k == 0) ? cur.y : 0.0f);
        float pg2 = (a2.x + a2.y) + ((k == 0) ? cur.z : 0.0f);
        float pg3 = (a3.x + a3.y) + ((k == 0) ? cur.w : 0.0f);
        pg0 += dpp_mov<0xB1>(pg0); pg0 += dpp_mov<0x4E>(pg0);
        pg1 += dpp_mov<0xB1>(pg1); pg1 += dpp_mov<0x4E>(pg1);
        pg2 += dpp_mov<0xB1>(pg2); pg2 += dpp_mov<0x4E>(pg2);
        pg3 += dpp_mov<0xB1>(pg3); pg3 += dpp_mov<0x4E>(pg3);

        const float gi = sigm(pg0), gf = sigm(pg1);
        const float gG = tanh_(pg2), go = sigm(pg3);
        c = gf * c + gi * gG;
        const float h = go * tanh_(c);
        h_last = h;
        if (k == 0) hbuf[p ^ 1][u] = h;

        float pd = woA * h;
        float pe = (k == 0) ? woB * h : 0.0f;
        pd += dpp_mov<0x114>(pd); pd += dpp_mov<0x118>(pd);   // row_shr 4,8
        pe += dpp_mov<0x114>(pe); pe += dpp_mov<0x118>(pe);
        if (wrRed) {
            red1[p][k][slot] = pd;
            if (k == 0) red1[p][4][slot] = pe;
        }
        bar();
        if (tid < 5) out[t * 5 + tid] = hsum32(red1[p][tid]) + boT;
        if (t >= S1 - 2) {
            const float n0 = hsum32(red1[p][0]) + bo0;
            const float n1 = hsum32(red1[p][1]) + bo1;
            if (t == S1 - 2) { p1x = obsA0 + n0; p1y = obsA1 + n1; }
            else             { p2x = obsB0 + n0; p2y = obsB1 + n1; }
        }
        p ^= 1;
    }

    // state handoff: c[128], h[128], positions[4]
    if (k == 0) { st[u] = c; st[128 + u] = h_last; }
    if (tid == 0) { st[256] = p1x; st[257] = p1y; st[258] = p2x; st[259] = p2y; }
}

// ---------- kernel 4b: phase-2 sequential LSTM ----------
__global__ __launch_bounds__(512, 2)
void k_seq2(const float* __restrict__ oth,
            const float* __restrict__ W_emb,
            const float* __restrict__ b_emb,
            const float* __restrict__ W_ih,
            const float* __restrict__ b_ih,
            const float* __restrict__ W_hh,
            const float* __restrict__ b_hh,
            const float* __restrict__ W_out,
            const float* __restrict__ b_out,
            const float* __restrict__ WT,
            float* __restrict__ out,
            const float* __restrict__ st) {
    const int tid  = threadIdx.x;
    const int wv   = tid >> 6;
    const int lane = tid & 63;
    const int u    = wv * 16 + (lane >> 2);
    const int k    = lane & 3;

    v2f whh[4][16];
#pragma unroll
    for (int g = 0; g < 4; g++) {
        const v2f* src = (const v2f*)(W_hh + (u + 128 * g) * HID + 32 * k);
#pragma unroll
        for (int j = 0; j < 16; j++) whh[g][j] = src[j];
    }
    v2f wie[4][8];
#pragma unroll
    for (int g = 0; g < 4; g++) {
        const v2f* src = (const v2f*)(W_ih + (u + 128 * g) * INDIM + 16 * k);
#pragma unroll
        for (int j = 0; j < 8; j++) wie[g][j] = src[j];
    }
    float biasg[4];
#pragma unroll
    for (int g = 0; g < 4; g++) biasg[g] = b_ih[u + 128 * g] + b_hh[u + 128 * g];

    const float woA = W_out[k * HID + u];
    const float woB = W_out[4 * HID + u];
    const float bo0 = b_out[0], bo1 = b_out[1];
    const float boT = (tid < 5) ? b_out[tid] : 0.0f;
    float we0 = 0.f, we1 = 0.f, be = 0.f;
    if (tid < 64) { we0 = W_emb[tid * 2]; we1 = W_emb[tid * 2 + 1]; be = b_emb[tid]; }

    __shared__ __align__(16) float hbuf[2][HID];
    __shared__ __align__(16) float e_lds[64];
    __shared__ __align__(16) float red2[5][32];
    __shared__ unsigned int smlo[2], smhi[2];

    // restore state
    float c = st[u];
    if (tid < HID) hbuf[0][tid] = st[128 + tid];
    const float p1x = st[256], p1y = st[257], p2x = st[258], p2y = st[259];
    float pcx = p2x, pcy = p2y;
    float dx = p2x - p1x, dy = p2y - p1y;
    int p = 0;
    if (tid == 0) { smlo[0] = 0; smlo[1] = 0; smhi[0] = 0; smhi[1] = 0; }
    if (tid < 64) {   // e for s=0
        float v = we0 * dx + we1 * dy + be;
        e_lds[tid] = v > 0.0f ? v : 0.0f;
    }
    __syncthreads();

    v4f nb[4];
    {
        const v4f* s0 = (const v4f*)(oth + (size_t)OBSN * NN * 2);
#pragma unroll
        for (int i = 0; i < 4; i++) nb[i] = s0[i * 512 + tid];
    }
    const float CST[7] = {-1.5f, -1.0f, -0.5f, 0.0f, 0.5f, 1.0f, 1.5f};
    const bool wrRed = (lane & 12) == 12;
    const int  slot  = wv * 4 + (lane >> 4);

    for (int s = 0; s < S2; ++s) {
        float bx[7], by[7];
#pragma unroll
        for (int j = 0; j < 7; j++) { bx[j] = CST[j] + pcx; by[j] = CST[j] + pcy; }

        unsigned long long m = 0ull;
#pragma unroll
        for (int i = 0; i < 4; i++) {
            const v4f q = nb[i];
            if (q.x > bx[0] && q.x < bx[6] && q.y > by[0] && q.y < by[6])
                m |= classify(q.x, q.y, bx, by);
            if (q.z > bx[0] && q.z < bx[6] && q.w > by[0] && q.w < by[6])
                m |= classify(q.z, q.w, bx, by);
        }
        {   // next-slice prefetch; lgkm-only barriers never drain it
            const int sn = (s + 1 < S2) ? s + 1 : s;
            const v4f* pf = (const v4f*)(oth + (size_t)(OBSN + sn) * NN * 2);
#pragma unroll
            for (int i = 0; i < 4; i++) nb[i] = pf[i * 512 + tid];
        }
        {   // rare LDS atomics replace the 12-bpermute 64-bit OR reduction
            const unsigned int lo = (unsigned int)m;
            const unsigned int hi = (unsigned int)(m >> 32);
            if (lo) atomicOr(&smlo[s & 1], lo);
            if (hi) atomicOr(&smhi[s & 1], hi);
        }
        bar();   // B1: mask + e_lds ready

        const unsigned long long mm =
            (unsigned long long)smlo[s & 1] | ((unsigned long long)smhi[s & 1] << 32);
        float og0 = (k == 0) ? biasg[0] : 0.0f;
        float og1 = (k == 0) ? biasg[1] : 0.0f;
        float og2 = (k == 0) ? biasg[2] : 0.0f;
        float og3 = (k == 0) ? biasg[3] : 0.0f;
        {
            unsigned long long mm2 = mm;
            int idx = 0;
            while (mm2) {
                const int j = __ffsll((long long)mm2) - 1;
                mm2 &= mm2 - 1;
                if ((idx & 3) == k) {
                    const float* wc = WT + j * 512 + u;
                    og0 += wc[0];
                    og1 += wc[128];
                    og2 += wc[256];
                    og3 += wc[384];
                }
                idx++;
            }
        }

        v2f a0 = {0.f, 0.f}, a1 = {0.f, 0.f}, a2 = {0.f, 0.f}, a3 = {0.f, 0.f};
        {
            const v4f* e4 = ((const v4f*)e_lds) + k * 4;
#pragma unroll
            for (int qq = 0; qq < 4; qq++) {
                const int q = (qq + k) & 3;
                const v4f ev = e4[q];
                const v2f el = ev.xy, eh = ev.zw;
                a0 = wie[0][2*q] * el + a0;  a0 = wie[0][2*q+1] * eh + a0;
                a1 = wie[1][2*q] * el + a1;  a1 = wie[1][2*q+1] * eh + a1;
                a2 = wie[2][2*q] * el + a2;  a2 = wie[2][2*q+1] * eh + a2;
                a3 = wie[3][2*q] * el + a3;  a3 = wie[3][2*q+1] * eh + a3;
            }
            const v4f* h4 = ((const v4f*)hbuf[p]) + k * 8;
#pragma unroll
            for (int qq = 0; qq < 8; qq++) {
                const int q = (qq + 2 * k) & 7;
                const v4f hv = h4[q];
                const v2f hl = hv.xy, hh2 = hv.zw;
                a0 = whh[0][2*q] * hl + a0;  a0 = whh[0][2*q+1] * hh2 + a0;
                a1 = whh[1][2*q] * hl + a1;  a1 = whh[1][2*q+1] * hh2 + a1;
                a2 = whh[2][2*q] * hl + a2;  a2 = whh[2][2*q+1] * hh2 + a2;
                a3 = whh[3][2*q] * hl + a3;  a3 = whh[3][2*q+1] * hh2 + a3;
            }
        }
        float pg0 = og0 + (a0.x + a0.y);
        float pg1 = og1 + (a1.x + a1.y);
        float pg2 = og2 + (a2.x + a2.y);
        float pg3 = og3 + (a3.x + a3.y);
        pg0 += dpp_mov<0xB1>(pg0); pg0 += dpp_mov<0x4E>(pg0);
        pg1 += dpp_mov<0xB1>(pg1); pg1 += dpp_mov<0x4E>(pg1);
        pg2 += dpp_mov<0xB1>(pg2); pg2 += dpp_mov<0x4E>(pg2);
        pg3 += dpp_mov<0xB1>(pg3); pg3 += dpp_mov<0x4E>(pg3);

        const float gi = sigm(pg0), gf = sigm(pg1);
        const float gG = tanh_(pg2), go = sigm(pg3);
        c = gf * c + gi * gG;
        const float h = go * tanh_(c);
        if (k == 0) hbuf[p ^ 1][u] = h;

        float pd = woA * h;
        float pe = (k == 0) ? woB * h : 0.0f;
        pd += dpp_mov<0x114>(pd); pd += dpp_mov<0x118>(pd);
        pe += dpp_mov<0x114>(pe); pe += dpp_mov<0x118>(pe);
        if (wrRed) {
            red2[k][slot] = pd;
            if (k == 0) red2[4][slot] = pe;
        }
        bar();   // B2: h + red ready

        const float n0 = hsum32(red2[0]) + bo0;
        const float n1 = hsum32(red2[1]) + bo1;
        if (tid < 5) out[(S1 + s) * 5 + tid] = hsum32(red2[tid]) + boT;
        if (tid == 0) { smlo[s & 1] = 0; smhi[s & 1] = 0; }   // re-arm for s+2
        dx = n0; dy = n1;
        pcx += n0; pcy += n1;
        if (tid < 64) {   // e for s+1; ordered vs step-s readers by B2
            float v = we0 * dx + we1 * dy + be;
            e_lds[tid] = v > 0.0f ? v : 0.0f;
        }
        p ^= 1;
    }
}

// ---------- launcher ----------
extern "C" void kernel_launch(void* const* d_in, const int* in_sizes, int n_in,
                              void* d_out, int out_size, void* d_ws, size_t ws_size,
                              hipStream_t stream) {
    const float* obs   = (const float*)d_in[0];
    const float* oth   = (const float*)d_in[1];
    const float* W_emb = (const float*)d_in[2];
    const float* b_emb = (const float*)d_in[3];
    const float* W_ih  = (const float*)d_in[4];
    const float* b_ih  = (const float*)d_in[5];
    const float* W_hh  = (const float*)d_in[6];
    const float* b_hh  = (const float*)d_in[7];
    const float* W_out = (const float*)d_in[8];
    const float* b_out = (const float*)d_in[9];
    float* out = (float*)d_out;

    unsigned long long* occm = (unsigned long long*)d_ws;                    // 16 KB
    float* G1 = (float*)((char*)d_ws + 16384);                               // 2047*512*4
    float* WT = (float*)((char*)d_ws + 16384 + (size_t)S1 * 512 * 4);        // 36*512*4
    float* st = (float*)((char*)d_ws + 16384 + (size_t)S1 * 512 * 4 + 36 * 512 * 4); // 260 f32

    k_occ1<<<S1, 256, 0, stream>>>(obs, oth, occm);
    k_tr<<<36, 512, 0, stream>>>(W_ih, WT);
    k_g1<<<S1, 256, 0, stream>>>(obs, W_emb, b_emb, W_ih, b_ih, b_hh, occm, G1);
    k_seq1<<<1, 512, 0, stream>>>(obs, W_hh, W_out, b_out, G1, out, st);
    k_seq2<<<1, 512, 0, stream>>>(oth, W_emb, b_emb, W_ih, b_ih, W_hh, b_hh,
                                  W_out, b_out, WT, out, st);
}